// Round 1
// 184.920 us; speedup vs baseline: 1.0787x; 1.0787x over previous
//
#include <hip/hip_runtime.h>
#include <math.h>

#define Bn 16
#define Gn 2048
#define Cn 128
#define Kn 16
#define QB 64       // queries per block (was 32)
#define CAP 192     // survivor cap per query (mean ~64; P(overflow) ~ 1e-16)
#define CAPS 200    // sbuf row stride in ushorts -> query bases 4 banks apart

__device__ __forceinline__ float med3f(float a, float b, float c) {
#if __has_builtin(__builtin_amdgcn_fmed3f)
    return __builtin_amdgcn_fmed3f(a, b, c);
#else
    return fmaxf(fminf(a, b), fminf(fmaxf(a, b), c));
#endif
}

// BIT-IDENTICAL in every phase (fp-consistent ranking incl. tie detection).
__device__ __forceinline__ float dist2(const float4 me, const float4 p) {
    float dot = fmaf(me.z, p.z, fmaf(me.y, p.y, me.x * p.x));
    return fmaf(-2.0f, dot, me.w + p.w);
}

__device__ __forceinline__ void ins16(float (&d)[16], float v) {
    float prev = d[0];
    d[0] = fminf(d[0], v);
    #pragma unroll
    for (int t = 1; t < 16; ++t) { float cur = d[t]; d[t] = med3f(v, prev, cur); prev = cur; }
}

// exact bitonic min-merge of sorted d[16] across the 8 lanes of a group
__device__ __forceinline__ void merge8(float (&d)[16]) {
    #pragma unroll
    for (int m = 1; m < 8; m <<= 1) {
        float e[16];
        #pragma unroll
        for (int t = 0; t < 16; ++t) e[t] = __shfl_xor(d[t], m);
        float x[16];
        #pragma unroll
        for (int t = 0; t < 16; ++t) x[t] = fminf(d[t], e[15 - t]);
        #pragma unroll
        for (int k = 8; k; k >>= 1) {
            #pragma unroll
            for (int t = 0; t < 16; ++t)
                if (!(t & k)) {
                    float lo = fminf(x[t], x[t + k]);
                    float hi = fmaxf(x[t], x[t + k]);
                    x[t] = lo; x[t + k] = hi;
                }
        }
        #pragma unroll
        for (int t = 0; t < 16; ++t) d[t] = x[t];
    }
}

__device__ __forceinline__ float gelu_exact(float x) {
    return 0.5f * x * (1.0f + erff(x * 0.70710678118654752440f));
}

// ---------------------------------------------------------------------------
// Fully fused: KNN (sample->filter->select) + gather/L2-pool + 2-layer MLP.
// 512 blocks x 512 threads; b = x&15 (batch b's 32 blocks all land on XCD b&7,
// so feat[b] stays L2-local); chunk = x>>4. Block owns 64 queries.
// LDS = union(pts 32KB, At 33KB) + sbuf 25KB + outb/tieb 8KB = 67.6KB
//   -> 2 blocks/CU -> all 512 blocks co-resident (zero tail), 16 waves/CU.
// ---------------------------------------------------------------------------
__global__ __launch_bounds__(512) void fused_kernel(const float* __restrict__ xyz,
                                                    const float* __restrict__ feat,
                                                    const float* __restrict__ W1,
                                                    const float* __restrict__ b1,
                                                    const float* __restrict__ W2,
                                                    const float* __restrict__ b2,
                                                    float* __restrict__ out) {
    __shared__ __align__(16) float smem0[QB * 132];   // 33792 B: pts (32KB) then At [64][132]
    __shared__ unsigned short sbuf[QB * CAPS];        // 25.0 KB survivors
    __shared__ int outb[QB * 16];                     // 4 KB final indices
    __shared__ int tieb[QB * 16];                     // 4 KB tie candidates
    float4* pts = reinterpret_cast<float4*>(smem0);   // [2048] xyz + |p|^2
    float*  At  = smem0;                              // [64][132] alias (pts dead by then)

    const int x     = blockIdx.x;
    const int b     = x & 15;
    const int chunk = x >> 4;                       // 0..31
    const int tid   = threadIdx.x;                  // 0..511
    const int lane  = tid & 63;
    const int w     = tid >> 6;                     // 0..7
    const int sub   = lane & 7;
    const int qg    = lane >> 3;                    // group within wave
    const int q     = w * 8 + qg;                   // 0..63
    const int g     = chunk * QB + q;

    // ---- stage xyz + |p|^2
    const float* xb = xyz + (size_t)b * Gn * 3;
    for (int i = tid; i < Gn; i += 512) {
        float px = xb[i * 3 + 0], py = xb[i * 3 + 1], pz = xb[i * 3 + 2];
        pts[i] = make_float4(px, py, pz, px * px + py * py + pz * pz);
    }
    __syncthreads();

    const float4 me = pts[g];
    const int base = sub << 8;
    const int c    = (37 * sub) & 255;              // bank stagger

    // ---- phase A: top16 of 512-sample (64/lane) -> conservative T0
    float d[16];
    #pragma unroll
    for (int t = 0; t < 16; ++t) d[t] = INFINITY;
    for (int j = 0; j < 64; j += 4) {
        float4 p0 = pts[base + ((j + 0 + c) & 255)];
        float4 p1 = pts[base + ((j + 1 + c) & 255)];
        float4 p2 = pts[base + ((j + 2 + c) & 255)];
        float4 p3 = pts[base + ((j + 3 + c) & 255)];
        ins16(d, dist2(me, p0)); ins16(d, dist2(me, p1));
        ins16(d, dist2(me, p2)); ins16(d, dist2(me, p3));
    }
    merge8(d);
    const float T0 = d[15];

    // ---- phase B: filter scan, ballot-append (no atomics)
    const unsigned lowm = (1u << sub) - 1;
    const int shft = lane & 56;                     // group base bit
    int cnt = 0;
    for (int j = 0; j < 256; j += 4) {
        int h0 = base + ((j + 0 + c) & 255);
        int h1 = base + ((j + 1 + c) & 255);
        int h2 = base + ((j + 2 + c) & 255);
        int h3 = base + ((j + 3 + c) & 255);
        float v0 = dist2(me, pts[h0]);
        float v1 = dist2(me, pts[h1]);
        float v2 = dist2(me, pts[h2]);
        float v3 = dist2(me, pts[h3]);
        #pragma unroll
        for (int u = 0; u < 4; ++u) {
            float v = (u == 0) ? v0 : (u == 1) ? v1 : (u == 2) ? v2 : v3;
            int   h = (u == 0) ? h0 : (u == 1) ? h1 : (u == 2) ? h2 : h3;
            bool pr = (v <= T0);
            unsigned long long m = __ballot(pr);
            unsigned gm = (unsigned)(m >> shft) & 0xFFu;
            if (pr) {
                int pp = cnt + __popc(gm & lowm);
                if (pp < CAP) sbuf[q * CAPS + pp] = (unsigned short)h;
            }
            cnt += __popc(gm);
        }
    }
    const int S = (cnt > CAP) ? CAP : cnt;          // S >= 16 always

    // ---- phase C: exact top16 of survivors -> exact T
    #pragma unroll
    for (int t = 0; t < 16; ++t) d[t] = INFINITY;
    for (int t = sub; t < S; t += 8) {
        int h = sbuf[q * CAPS + t];
        ins16(d, dist2(me, pts[h]));
    }
    merge8(d);
    const float T = d[15];

    // ---- phase D: emit index set (ballot-append; ties lowest-index-first)
    int nl = 0, nt = 0;
    for (int t = sub; t < S; t += 8) {
        int h = sbuf[q * CAPS + t];
        float v = dist2(me, pts[h]);
        bool pl = (v < T), pt = (v == T);
        unsigned long long ml = __ballot(pl);
        unsigned long long mt = __ballot(pt);
        unsigned gml = (unsigned)(ml >> shft) & 0xFFu;
        unsigned gmt = (unsigned)(mt >> shft) & 0xFFu;
        if (pl) outb[q * 16 + nl + __popc(gml & lowm)] = h;       // nl_total <= 15
        if (pt) { int pp = nt + __popc(gmt & lowm); if (pp < 16) tieb[q * 16 + pp] = h; }
        nl += __popc(gml);
        nt += __popc(gmt);
    }
    if (sub == 0) {
        int mfill = nl;                              // < 16
        int need  = 16 - mfill;
        int tc = (nt > 16) ? 16 : nt;
        for (int s = 0; s < need; ++s) {
            int best = 0x7fffffff, bp = -1;
            for (int u = 0; u < tc; ++u) {
                int vv = tieb[q * 16 + u];
                if (vv < best) { best = vv; bp = u; }
            }
            if (bp >= 0) { tieb[q * 16 + bp] = 0x7fffffff; outb[q * 16 + mfill + s] = best; }
        }
    }
    __syncthreads();                                 // pts dead; outb ready

    // ---- gather + L2 pool: half-wave per query, float4 lanes (512B coalesced)
    const float4* fb4 = (const float4*)(feat + (size_t)b * Gn * Cn);
    const int cl = lane & 31;
    #pragma unroll
    for (int pass = 0; pass < 4; ++pass) {
        int qq = w * 8 + pass * 2 + (lane >> 5);
        float4 a = make_float4(0.f, 0.f, 0.f, 0.f);
        #pragma unroll
        for (int half = 0; half < 2; ++half) {
            int hs[8]; float4 f[8];
            #pragma unroll
            for (int k = 0; k < 8; ++k) hs[k] = outb[qq * 16 + half * 8 + k];
            #pragma unroll
            for (int k = 0; k < 8; ++k) f[k] = fb4[(size_t)hs[k] * 32 + cl];
            #pragma unroll
            for (int k = 0; k < 8; ++k) {
                a.x = fmaf(f[k].x, f[k].x, a.x);
                a.y = fmaf(f[k].y, f[k].y, a.y);
                a.z = fmaf(f[k].z, f[k].z, a.z);
                a.w = fmaf(f[k].w, f[k].w, a.w);
            }
        }
        float4 r = make_float4(sqrtf(a.x), sqrtf(a.y), sqrtf(a.z), sqrtf(a.w));
        *(float4*)&At[qq * 132 + cl * 4] = r;        // row stride 132: no conflicts
    }
    __syncthreads();

    // ---- MLP: thread = 2 rows x 8 cols; W register-pipelined from L1/L2
    const int j0 = tid & 15;                         // float4-col pair j0*2, j0*2+1
    const int rg = tid >> 4;                         // rows rg*2, rg*2+1 (0..63)
    float acc[2][8];

    // ---- layer 1
    {
        const float4* Wv = (const float4*)W1;
        float4 ba = ((const float4*)b1)[j0 * 2];
        float4 bb = ((const float4*)b1)[j0 * 2 + 1];
        #pragma unroll
        for (int r = 0; r < 2; ++r) {
            acc[r][0] = ba.x; acc[r][1] = ba.y; acc[r][2] = ba.z; acc[r][3] = ba.w;
            acc[r][4] = bb.x; acc[r][5] = bb.y; acc[r][6] = bb.z; acc[r][7] = bb.w;
        }
        float4 cw[4][2];
        #pragma unroll
        for (int u = 0; u < 4; ++u) {
            cw[u][0] = Wv[u * 32 + j0 * 2];
            cw[u][1] = Wv[u * 32 + j0 * 2 + 1];
        }
        for (int i = 0; i < 128; i += 4) {
            float4 nw[4][2];
            int ii = (i + 4) & 127;
            #pragma unroll
            for (int u = 0; u < 4; ++u) {
                nw[u][0] = Wv[(ii + u) * 32 + j0 * 2];
                nw[u][1] = Wv[(ii + u) * 32 + j0 * 2 + 1];
            }
            #pragma unroll
            for (int r = 0; r < 2; ++r) {
                float4 a = *(const float4*)&At[(rg * 2 + r) * 132 + i];
                float av[4] = {a.x, a.y, a.z, a.w};
                #pragma unroll
                for (int u = 0; u < 4; ++u) {
                    acc[r][0] = fmaf(av[u], cw[u][0].x, acc[r][0]);
                    acc[r][1] = fmaf(av[u], cw[u][0].y, acc[r][1]);
                    acc[r][2] = fmaf(av[u], cw[u][0].z, acc[r][2]);
                    acc[r][3] = fmaf(av[u], cw[u][0].w, acc[r][3]);
                    acc[r][4] = fmaf(av[u], cw[u][1].x, acc[r][4]);
                    acc[r][5] = fmaf(av[u], cw[u][1].y, acc[r][5]);
                    acc[r][6] = fmaf(av[u], cw[u][1].z, acc[r][6]);
                    acc[r][7] = fmaf(av[u], cw[u][1].w, acc[r][7]);
                }
            }
            #pragma unroll
            for (int u = 0; u < 4; ++u) { cw[u][0] = nw[u][0]; cw[u][1] = nw[u][1]; }
        }
    }
    __syncthreads();
    #pragma unroll
    for (int r = 0; r < 2; ++r) {
        float4 g0, g1;
        g0.x = gelu_exact(acc[r][0]); g0.y = gelu_exact(acc[r][1]);
        g0.z = gelu_exact(acc[r][2]); g0.w = gelu_exact(acc[r][3]);
        g1.x = gelu_exact(acc[r][4]); g1.y = gelu_exact(acc[r][5]);
        g1.z = gelu_exact(acc[r][6]); g1.w = gelu_exact(acc[r][7]);
        *(float4*)&At[(rg * 2 + r) * 132 + j0 * 8]     = g0;
        *(float4*)&At[(rg * 2 + r) * 132 + j0 * 8 + 4] = g1;
    }
    __syncthreads();

    // ---- layer 2
    {
        const float4* Wv = (const float4*)W2;
        float4 ba = ((const float4*)b2)[j0 * 2];
        float4 bb = ((const float4*)b2)[j0 * 2 + 1];
        #pragma unroll
        for (int r = 0; r < 2; ++r) {
            acc[r][0] = ba.x; acc[r][1] = ba.y; acc[r][2] = ba.z; acc[r][3] = ba.w;
            acc[r][4] = bb.x; acc[r][5] = bb.y; acc[r][6] = bb.z; acc[r][7] = bb.w;
        }
        float4 cw[4][2];
        #pragma unroll
        for (int u = 0; u < 4; ++u) {
            cw[u][0] = Wv[u * 32 + j0 * 2];
            cw[u][1] = Wv[u * 32 + j0 * 2 + 1];
        }
        for (int i = 0; i < 128; i += 4) {
            float4 nw[4][2];
            int ii = (i + 4) & 127;
            #pragma unroll
            for (int u = 0; u < 4; ++u) {
                nw[u][0] = Wv[(ii + u) * 32 + j0 * 2];
                nw[u][1] = Wv[(ii + u) * 32 + j0 * 2 + 1];
            }
            #pragma unroll
            for (int r = 0; r < 2; ++r) {
                float4 a = *(const float4*)&At[(rg * 2 + r) * 132 + i];
                float av[4] = {a.x, a.y, a.z, a.w};
                #pragma unroll
                for (int u = 0; u < 4; ++u) {
                    acc[r][0] = fmaf(av[u], cw[u][0].x, acc[r][0]);
                    acc[r][1] = fmaf(av[u], cw[u][0].y, acc[r][1]);
                    acc[r][2] = fmaf(av[u], cw[u][0].z, acc[r][2]);
                    acc[r][3] = fmaf(av[u], cw[u][0].w, acc[r][3]);
                    acc[r][4] = fmaf(av[u], cw[u][1].x, acc[r][4]);
                    acc[r][5] = fmaf(av[u], cw[u][1].y, acc[r][5]);
                    acc[r][6] = fmaf(av[u], cw[u][1].z, acc[r][6]);
                    acc[r][7] = fmaf(av[u], cw[u][1].w, acc[r][7]);
                }
            }
            #pragma unroll
            for (int u = 0; u < 4; ++u) { cw[u][0] = nw[u][0]; cw[u][1] = nw[u][1]; }
        }
    }
    float4* outv = (float4*)out;
    #pragma unroll
    for (int r = 0; r < 2; ++r) {
        size_t row = (size_t)b * Gn + chunk * QB + rg * 2 + r;
        outv[row * 32 + j0 * 2]     = make_float4(acc[r][0], acc[r][1], acc[r][2], acc[r][3]);
        outv[row * 32 + j0 * 2 + 1] = make_float4(acc[r][4], acc[r][5], acc[r][6], acc[r][7]);
    }
}

// ---------------------------------------------------------------------------
extern "C" void kernel_launch(void* const* d_in, const int* in_sizes, int n_in,
                              void* d_out, int out_size, void* d_ws, size_t ws_size,
                              hipStream_t stream) {
    const float* xyz  = (const float*)d_in[0];
    const float* feat = (const float*)d_in[1];
    const float* W1   = (const float*)d_in[2];
    const float* b1   = (const float*)d_in[3];
    const float* W2   = (const float*)d_in[4];
    const float* b2   = (const float*)d_in[5];
    float* out = (float*)d_out;

    fused_kernel<<<512, 512, 0, stream>>>(xyz, feat, W1, b1, W2, b2, out);
}

// Round 2
// 159.127 us; speedup vs baseline: 1.2536x; 1.1621x over previous
//
#include <hip/hip_runtime.h>
#include <math.h>

#define Bn 16
#define Gn 2048
#define Cn 128
#define Kn 16
#define QB 64       // queries per block
#define CAP 192     // survivor cap per query (mean ~64; P(overflow) ~ 1e-16)
#define CAPS 200    // sbuf row stride in ushorts -> query bases 4 banks apart
#define AS  136     // A-tile row stride in bf16 elems: 272B = 17*16B (aligned, 2-way banks)

typedef __attribute__((ext_vector_type(8))) short bf16x8;
typedef __attribute__((ext_vector_type(4))) float f32x4;

__device__ __forceinline__ unsigned short f2bf(float x) {   // RNE fp32->bf16
    unsigned int u = __float_as_uint(x);
    unsigned int r = (u + 0x7fffu + ((u >> 16) & 1u)) >> 16;
    return (unsigned short)r;
}
__device__ __forceinline__ float bf2f(unsigned short h) {
    return __uint_as_float(((unsigned int)h) << 16);
}

__device__ __forceinline__ float med3f(float a, float b, float c) {
#if __has_builtin(__builtin_amdgcn_fmed3f)
    return __builtin_amdgcn_fmed3f(a, b, c);
#else
    return fmaxf(fminf(a, b), fminf(fmaxf(a, b), c));
#endif
}

// BIT-IDENTICAL in every phase (fp-consistent ranking incl. tie detection).
__device__ __forceinline__ float dist2(const float4 me, const float4 p) {
    float dot = fmaf(me.z, p.z, fmaf(me.y, p.y, me.x * p.x));
    return fmaf(-2.0f, dot, me.w + p.w);
}

__device__ __forceinline__ void ins16(float (&d)[16], float v) {
    float prev = d[0];
    d[0] = fminf(d[0], v);
    #pragma unroll
    for (int t = 1; t < 16; ++t) { float cur = d[t]; d[t] = med3f(v, prev, cur); prev = cur; }
}

// exact bitonic min-merge of sorted d[16] across the 8 lanes of a group
__device__ __forceinline__ void merge8(float (&d)[16]) {
    #pragma unroll
    for (int m = 1; m < 8; m <<= 1) {
        float e[16];
        #pragma unroll
        for (int t = 0; t < 16; ++t) e[t] = __shfl_xor(d[t], m);
        float x[16];
        #pragma unroll
        for (int t = 0; t < 16; ++t) x[t] = fminf(d[t], e[15 - t]);
        #pragma unroll
        for (int k = 8; k; k >>= 1) {
            #pragma unroll
            for (int t = 0; t < 16; ++t)
                if (!(t & k)) {
                    float lo = fminf(x[t], x[t + k]);
                    float hi = fmaxf(x[t], x[t + k]);
                    x[t] = lo; x[t + k] = hi;
                }
        }
        #pragma unroll
        for (int t = 0; t < 16; ++t) d[t] = x[t];
    }
}

__device__ __forceinline__ float gelu_exact(float x) {
    return 0.5f * x * (1.0f + erff(x * 0.70710678118654752440f));
}

// ---------------------------------------------------------------------------
// prep_w: W[k][n] fp32 -> Wt[n][k] split bf16 (hi/lo) in workspace.
// ws layout (ushorts): Wt1_hi[128*128] | Wt1_lo | Wt2_hi | Wt2_lo  (128 KB)
// ---------------------------------------------------------------------------
__global__ __launch_bounds__(256) void prep_w(const float* __restrict__ W1,
                                              const float* __restrict__ W2,
                                              unsigned short* __restrict__ ws) {
    int t = blockIdx.x * 256 + threadIdx.x;     // 0..16383 (grid 64)
    if (t < 16384) {
        int k = t >> 7, n = t & 127;
        float w = W1[t];
        unsigned short h = f2bf(w);
        unsigned short l = f2bf(w - bf2f(h));   // Dekker split: w-hi exact in fp32
        ws[n * 128 + k]          = h;
        ws[16384 + n * 128 + k]  = l;
        w = W2[t];
        h = f2bf(w);
        l = f2bf(w - bf2f(h));
        ws[32768 + n * 128 + k]  = h;
        ws[49152 + n * 128 + k]  = l;
    }
}

// ---------------------------------------------------------------------------
// Fully fused: KNN (sample->filter->select) + gather/L2-pool + MFMA MLP.
// 512 blocks x 512 threads; b = x&15; chunk = x>>4. Block owns 64 queries.
// LDS = union(pts 32KB, Ahi/Alo 34KB) + sbuf 25KB + outb/tieb 8KB = 68.6KB
//   -> 2 blocks/CU, all 512 blocks co-resident.
// MLP: split-bf16 MFMA 16x16x32 (Ahi*Bhi + Ahi*Blo + Alo*Bhi, err ~2^-17);
// B-frags contiguous 16B loads from transposed Wt in d_ws (L2-resident).
// ---------------------------------------------------------------------------
__global__ __launch_bounds__(512) void fused_kernel(const float* __restrict__ xyz,
                                                    const float* __restrict__ feat,
                                                    const float* __restrict__ b1,
                                                    const float* __restrict__ b2,
                                                    const unsigned short* __restrict__ wt,
                                                    float* __restrict__ out) {
    __shared__ __align__(16) float smem0[8704];       // pts (32KB) U Ahi/Alo (34KB)
    __shared__ unsigned short sbuf[QB * CAPS];        // 25.0 KB survivors
    __shared__ int outb[QB * 16];                     // 4 KB final indices
    __shared__ int tieb[QB * 16];                     // 4 KB tie candidates
    float4* pts = reinterpret_cast<float4*>(smem0);   // [2048] xyz + |p|^2
    unsigned short* Ahi = reinterpret_cast<unsigned short*>(smem0);  // [64][AS]
    unsigned short* Alo = Ahi + QB * AS;                             // [64][AS]

    const int x     = blockIdx.x;
    const int b     = x & 15;
    const int chunk = x >> 4;                       // 0..31
    const int tid   = threadIdx.x;                  // 0..511
    const int lane  = tid & 63;
    const int w     = tid >> 6;                     // 0..7
    const int sub   = lane & 7;
    const int qg    = lane >> 3;                    // group within wave
    const int q     = w * 8 + qg;                   // 0..63
    const int g     = chunk * QB + q;

    // ---- stage xyz + |p|^2
    const float* xb = xyz + (size_t)b * Gn * 3;
    for (int i = tid; i < Gn; i += 512) {
        float px = xb[i * 3 + 0], py = xb[i * 3 + 1], pz = xb[i * 3 + 2];
        pts[i] = make_float4(px, py, pz, px * px + py * py + pz * pz);
    }
    __syncthreads();

    const float4 me = pts[g];
    const int base = sub << 8;
    const int c    = (37 * sub) & 255;              // bank stagger

    // ---- phase A: top16 of 512-sample (64/lane) -> conservative T0
    float d[16];
    #pragma unroll
    for (int t = 0; t < 16; ++t) d[t] = INFINITY;
    for (int j = 0; j < 64; j += 4) {
        float4 p0 = pts[base + ((j + 0 + c) & 255)];
        float4 p1 = pts[base + ((j + 1 + c) & 255)];
        float4 p2 = pts[base + ((j + 2 + c) & 255)];
        float4 p3 = pts[base + ((j + 3 + c) & 255)];
        ins16(d, dist2(me, p0)); ins16(d, dist2(me, p1));
        ins16(d, dist2(me, p2)); ins16(d, dist2(me, p3));
    }
    merge8(d);
    const float T0 = d[15];

    // ---- phase B: filter scan, ballot-append (no atomics)
    const unsigned lowm = (1u << sub) - 1;
    const int shft = lane & 56;                     // group base bit
    int cnt = 0;
    for (int j = 0; j < 256; j += 4) {
        int h0 = base + ((j + 0 + c) & 255);
        int h1 = base + ((j + 1 + c) & 255);
        int h2 = base + ((j + 2 + c) & 255);
        int h3 = base + ((j + 3 + c) & 255);
        float v0 = dist2(me, pts[h0]);
        float v1 = dist2(me, pts[h1]);
        float v2 = dist2(me, pts[h2]);
        float v3 = dist2(me, pts[h3]);
        #pragma unroll
        for (int u = 0; u < 4; ++u) {
            float v = (u == 0) ? v0 : (u == 1) ? v1 : (u == 2) ? v2 : v3;
            int   h = (u == 0) ? h0 : (u == 1) ? h1 : (u == 2) ? h2 : h3;
            bool pr = (v <= T0);
            unsigned long long m = __ballot(pr);
            unsigned gm = (unsigned)(m >> shft) & 0xFFu;
            if (pr) {
                int pp = cnt + __popc(gm & lowm);
                if (pp < CAP) sbuf[q * CAPS + pp] = (unsigned short)h;
            }
            cnt += __popc(gm);
        }
    }
    const int S = (cnt > CAP) ? CAP : cnt;          // S >= 16 always

    // ---- phase C: exact top16 of survivors -> exact T
    #pragma unroll
    for (int t = 0; t < 16; ++t) d[t] = INFINITY;
    for (int t = sub; t < S; t += 8) {
        int h = sbuf[q * CAPS + t];
        ins16(d, dist2(me, pts[h]));
    }
    merge8(d);
    const float T = d[15];

    // ---- phase D: emit index set (ballot-append; ties lowest-index-first)
    int nl = 0, nt = 0;
    for (int t = sub; t < S; t += 8) {
        int h = sbuf[q * CAPS + t];
        float v = dist2(me, pts[h]);
        bool pl = (v < T), pt = (v == T);
        unsigned long long ml = __ballot(pl);
        unsigned long long mt = __ballot(pt);
        unsigned gml = (unsigned)(ml >> shft) & 0xFFu;
        unsigned gmt = (unsigned)(mt >> shft) & 0xFFu;
        if (pl) outb[q * 16 + nl + __popc(gml & lowm)] = h;       // nl_total <= 15
        if (pt) { int pp = nt + __popc(gmt & lowm); if (pp < 16) tieb[q * 16 + pp] = h; }
        nl += __popc(gml);
        nt += __popc(gmt);
    }
    if (sub == 0) {
        int mfill = nl;                              // < 16
        int need  = 16 - mfill;
        int tc = (nt > 16) ? 16 : nt;
        for (int s = 0; s < need; ++s) {
            int best = 0x7fffffff, bp = -1;
            for (int u = 0; u < tc; ++u) {
                int vv = tieb[q * 16 + u];
                if (vv < best) { best = vv; bp = u; }
            }
            if (bp >= 0) { tieb[q * 16 + bp] = 0x7fffffff; outb[q * 16 + mfill + s] = best; }
        }
    }
    __syncthreads();                                 // pts dead; outb ready

    // ---- gather + L2 pool: half-wave per query, float4 lanes (512B coalesced)
    // write pooled A directly as split-bf16 into Ahi/Alo (aliases pts)
    const float4* fb4 = (const float4*)(feat + (size_t)b * Gn * Cn);
    const int cl = lane & 31;
    #pragma unroll
    for (int pass = 0; pass < 4; ++pass) {
        int qq = w * 8 + pass * 2 + (lane >> 5);
        float4 a = make_float4(0.f, 0.f, 0.f, 0.f);
        #pragma unroll
        for (int half = 0; half < 2; ++half) {
            int hs[8]; float4 f[8];
            #pragma unroll
            for (int k = 0; k < 8; ++k) hs[k] = outb[qq * 16 + half * 8 + k];
            #pragma unroll
            for (int k = 0; k < 8; ++k) f[k] = fb4[(size_t)hs[k] * 32 + cl];
            #pragma unroll
            for (int k = 0; k < 8; ++k) {
                a.x = fmaf(f[k].x, f[k].x, a.x);
                a.y = fmaf(f[k].y, f[k].y, a.y);
                a.z = fmaf(f[k].z, f[k].z, a.z);
                a.w = fmaf(f[k].w, f[k].w, a.w);
            }
        }
        float r0 = sqrtf(a.x), r1 = sqrtf(a.y), r2 = sqrtf(a.z), r3 = sqrtf(a.w);
        unsigned short h0 = f2bf(r0), h1 = f2bf(r1), h2 = f2bf(r2), h3 = f2bf(r3);
        ushort4 hv = make_ushort4(h0, h1, h2, h3);
        ushort4 lv = make_ushort4(f2bf(r0 - bf2f(h0)), f2bf(r1 - bf2f(h1)),
                                  f2bf(r2 - bf2f(h2)), f2bf(r3 - bf2f(h3)));
        *(ushort4*)&Ahi[qq * AS + cl * 4] = hv;
        *(ushort4*)&Alo[qq * AS + cl * 4] = lv;
    }
    __syncthreads();

    // ---- MLP via split-bf16 MFMA ------------------------------------------
    // wave w: row-block rows rowg..rowg+15 (rowg=(w&3)*16), cols colg0..colg0+63
    // A-frag: lane l -> A[rowg+(l&15)][kk + (l>>4)*8 + j]  (contiguous bf16x8)
    // B-frag: lane l -> Wt[colg0+cb*16+(l&15)][kk + (l>>4)*8 + j] (contiguous)
    // C/D:    lane l, reg r -> C[(l>>4)*4 + r][l&15]   (m89-verified)
    const int l15  = lane & 15;
    const int kofs = (lane >> 4) * 8;
    const int rowg = (w & 3) * 16;
    const int colg0 = (w >> 2) * 64;
    const unsigned short* wt1h = wt;            // +16384: lo; +32768: W2 hi; +49152: W2 lo
    f32x4 acc[4];

    // ---- layer 1: h = gelu(pooled @ W1 + b1)
    #pragma unroll
    for (int cb = 0; cb < 4; ++cb) {
        float bv = b1[colg0 + cb * 16 + l15];
        acc[cb] = (f32x4){bv, bv, bv, bv};
    }
    #pragma unroll
    for (int kk = 0; kk < 128; kk += 32) {
        bf16x8 ah = *(const bf16x8*)&Ahi[rowg * AS + l15 * AS + kk + kofs];
        bf16x8 al = *(const bf16x8*)&Alo[rowg * AS + l15 * AS + kk + kofs];
        #pragma unroll
        for (int cb = 0; cb < 4; ++cb) {
            const unsigned short* wp = wt1h + (size_t)(colg0 + cb * 16 + l15) * 128 + kk + kofs;
            bf16x8 bh = *(const bf16x8*)wp;
            bf16x8 bl = *(const bf16x8*)(wp + 16384);
            acc[cb] = __builtin_amdgcn_mfma_f32_16x16x32_bf16(ah, bh, acc[cb], 0, 0, 0);
            acc[cb] = __builtin_amdgcn_mfma_f32_16x16x32_bf16(ah, bl, acc[cb], 0, 0, 0);
            acc[cb] = __builtin_amdgcn_mfma_f32_16x16x32_bf16(al, bh, acc[cb], 0, 0, 0);
        }
    }
    __syncthreads();                            // all layer-1 A reads done
    #pragma unroll
    for (int cb = 0; cb < 4; ++cb) {
        #pragma unroll
        for (int r = 0; r < 4; ++r) {
            float gv = gelu_exact(acc[cb][r]);
            unsigned short h = f2bf(gv);
            int row = rowg + (lane >> 4) * 4 + r;
            int col = colg0 + cb * 16 + l15;
            Ahi[row * AS + col] = h;
            Alo[row * AS + col] = f2bf(gv - bf2f(h));
        }
    }
    __syncthreads();                            // h tile complete

    // ---- layer 2: out = h @ W2 + b2
    #pragma unroll
    for (int cb = 0; cb < 4; ++cb) {
        float bv = b2[colg0 + cb * 16 + l15];
        acc[cb] = (f32x4){bv, bv, bv, bv};
    }
    #pragma unroll
    for (int kk = 0; kk < 128; kk += 32) {
        bf16x8 ah = *(const bf16x8*)&Ahi[rowg * AS + l15 * AS + kk + kofs];
        bf16x8 al = *(const bf16x8*)&Alo[rowg * AS + l15 * AS + kk + kofs];
        #pragma unroll
        for (int cb = 0; cb < 4; ++cb) {
            const unsigned short* wp = wt1h + 32768 + (size_t)(colg0 + cb * 16 + l15) * 128 + kk + kofs;
            bf16x8 bh = *(const bf16x8*)wp;
            bf16x8 bl = *(const bf16x8*)(wp + 16384);
            acc[cb] = __builtin_amdgcn_mfma_f32_16x16x32_bf16(ah, bh, acc[cb], 0, 0, 0);
            acc[cb] = __builtin_amdgcn_mfma_f32_16x16x32_bf16(ah, bl, acc[cb], 0, 0, 0);
            acc[cb] = __builtin_amdgcn_mfma_f32_16x16x32_bf16(al, bh, acc[cb], 0, 0, 0);
        }
    }
    // ---- store: lanes cover 16 consecutive cols (64B segments x 4 row-groups)
    const size_t orow0 = (size_t)b * Gn + (size_t)chunk * QB + rowg + (lane >> 4) * 4;
    #pragma unroll
    for (int cb = 0; cb < 4; ++cb) {
        #pragma unroll
        for (int r = 0; r < 4; ++r) {
            out[(orow0 + r) * Cn + colg0 + cb * 16 + l15] = acc[cb][r];
        }
    }
}

// ---------------------------------------------------------------------------
extern "C" void kernel_launch(void* const* d_in, const int* in_sizes, int n_in,
                              void* d_out, int out_size, void* d_ws, size_t ws_size,
                              hipStream_t stream) {
    const float* xyz  = (const float*)d_in[0];
    const float* feat = (const float*)d_in[1];
    const float* W1   = (const float*)d_in[2];
    const float* b1   = (const float*)d_in[3];
    const float* W2   = (const float*)d_in[4];
    const float* b2   = (const float*)d_in[5];
    float* out = (float*)d_out;
    unsigned short* wt = (unsigned short*)d_ws;    // 128 KB: Wt1 hi/lo, Wt2 hi/lo

    prep_w<<<64, 256, 0, stream>>>(W1, W2, wt);
    fused_kernel<<<512, 512, 0, stream>>>(xyz, feat, b1, b2, wt, out);
}

// Round 3
// 158.005 us; speedup vs baseline: 1.2625x; 1.0071x over previous
//
#include <hip/hip_runtime.h>
#include <math.h>

#define Bn 16
#define Gn 2048
#define Cn 128
#define Kn 16
#define QB 64       // queries per block
#define LCAP 42     // per-lane survivor cap (mean ~8; stride 84B = 21 banks, gcd(21,32)=1)
#define AS  136     // A-tile row stride in bf16 elems: 272B = 17*16B (aligned, 2-way banks)

typedef __attribute__((ext_vector_type(8))) short bf16x8;
typedef __attribute__((ext_vector_type(4))) float f32x4;

__device__ __forceinline__ unsigned short f2bf(float x) {   // RNE fp32->bf16
    unsigned int u = __float_as_uint(x);
    unsigned int r = (u + 0x7fffu + ((u >> 16) & 1u)) >> 16;
    return (unsigned short)r;
}
__device__ __forceinline__ float bf2f(unsigned short h) {
    return __uint_as_float(((unsigned int)h) << 16);
}

__device__ __forceinline__ float med3f(float a, float b, float c) {
#if __has_builtin(__builtin_amdgcn_fmed3f)
    return __builtin_amdgcn_fmed3f(a, b, c);
#else
    return fmaxf(fminf(a, b), fminf(fmaxf(a, b), c));
#endif
}

// BIT-IDENTICAL in every phase (fp-consistent ranking incl. tie detection).
__device__ __forceinline__ float dist2(const float4 me, const float4 p) {
    float dot = fmaf(me.z, p.z, fmaf(me.y, p.y, me.x * p.x));
    return fmaf(-2.0f, dot, me.w + p.w);
}

__device__ __forceinline__ void ins16(float (&d)[16], float v) {
    float prev = d[0];
    d[0] = fminf(d[0], v);
    #pragma unroll
    for (int t = 1; t < 16; ++t) { float cur = d[t]; d[t] = med3f(v, prev, cur); prev = cur; }
}

// exact bitonic min-merge of sorted d[16] across the 8 lanes of a group
__device__ __forceinline__ void merge8(float (&d)[16]) {
    #pragma unroll
    for (int m = 1; m < 8; m <<= 1) {
        float e[16];
        #pragma unroll
        for (int t = 0; t < 16; ++t) e[t] = __shfl_xor(d[t], m);
        float x[16];
        #pragma unroll
        for (int t = 0; t < 16; ++t) x[t] = fminf(d[t], e[15 - t]);
        #pragma unroll
        for (int k = 8; k; k >>= 1) {
            #pragma unroll
            for (int t = 0; t < 16; ++t)
                if (!(t & k)) {
                    float lo = fminf(x[t], x[t + k]);
                    float hi = fmaxf(x[t], x[t + k]);
                    x[t] = lo; x[t + k] = hi;
                }
        }
        #pragma unroll
        for (int t = 0; t < 16; ++t) d[t] = x[t];
    }
}

__device__ __forceinline__ float gelu_exact(float x) {
    return 0.5f * x * (1.0f + erff(x * 0.70710678118654752440f));
}

// ---------------------------------------------------------------------------
// prep_w: W[k][n] fp32 -> Wt[n][k] split bf16 (hi/lo) in workspace.
// ws layout (ushorts): Wt1_hi[128*128] | Wt1_lo | Wt2_hi | Wt2_lo  (128 KB)
// ---------------------------------------------------------------------------
__global__ __launch_bounds__(256) void prep_w(const float* __restrict__ W1,
                                              const float* __restrict__ W2,
                                              unsigned short* __restrict__ ws) {
    int t = blockIdx.x * 256 + threadIdx.x;     // 0..16383 (grid 64)
    if (t < 16384) {
        int k = t >> 7, n = t & 127;
        float w = W1[t];
        unsigned short h = f2bf(w);
        unsigned short l = f2bf(w - bf2f(h));   // Dekker split: w-hi exact in fp32
        ws[n * 128 + k]          = h;
        ws[16384 + n * 128 + k]  = l;
        w = W2[t];
        h = f2bf(w);
        l = f2bf(w - bf2f(h));
        ws[32768 + n * 128 + k]  = h;
        ws[49152 + n * 128 + k]  = l;
    }
}

// ---------------------------------------------------------------------------
// Fully fused: KNN (sample->filter->select) + gather/L2-pool + MFMA MLP.
// 512 blocks x 512 threads; b = x&15; chunk = x>>4. Block owns 64 queries.
// Survivors: PER-LANE lists (predicated append, no ballots in the hot scan).
// LDS = union(pts 32KB, Ahi/Alo 34KB) + sbuf 42KB + outb/tieb 4KB = 80KB
//   -> exactly 2 blocks/CU, all 512 blocks co-resident.
// MLP: split-bf16 MFMA 16x16x32 (Ahi*Bhi + Ahi*Blo + Alo*Bhi, err ~2^-17).
// ---------------------------------------------------------------------------
__global__ __launch_bounds__(512) void fused_kernel(const float* __restrict__ xyz,
                                                    const float* __restrict__ feat,
                                                    const float* __restrict__ b1,
                                                    const float* __restrict__ b2,
                                                    const unsigned short* __restrict__ wt,
                                                    float* __restrict__ out) {
    __shared__ __align__(16) float smem0[8704];       // 34816B: pts(32KB) U Ahi/Alo(34KB)
    __shared__ unsigned short sbuf[QB * 8 * LCAP];    // 43008 B per-lane survivors
    __shared__ unsigned short outb[QB * 16];          // 2 KB final indices
    __shared__ unsigned short tieb[QB * 16];          // 2 KB tie candidates
    float4* pts = reinterpret_cast<float4*>(smem0);   // [2048] xyz + |p|^2
    unsigned short* Ahi = reinterpret_cast<unsigned short*>(smem0);  // [64][AS]
    unsigned short* Alo = Ahi + QB * AS;                             // [64][AS]

    const int x     = blockIdx.x;
    const int b     = x & 15;
    const int chunk = x >> 4;                       // 0..31
    const int tid   = threadIdx.x;                  // 0..511
    const int lane  = tid & 63;
    const int w     = tid >> 6;                     // 0..7
    const int sub   = lane & 7;
    const int qg    = lane >> 3;                    // group within wave
    const int q     = w * 8 + qg;                   // 0..63
    const int g     = chunk * QB + q;

    // ---- stage xyz + |p|^2
    const float* xb = xyz + (size_t)b * Gn * 3;
    for (int i = tid; i < Gn; i += 512) {
        float px = xb[i * 3 + 0], py = xb[i * 3 + 1], pz = xb[i * 3 + 2];
        pts[i] = make_float4(px, py, pz, px * px + py * py + pz * pz);
    }
    __syncthreads();

    const float4 me = pts[g];
    const int base = sub << 8;
    const int c    = (37 * sub) & 255;              // bank stagger

    // ---- phase A: top16 of 512-sample (64/lane) -> conservative T0
    float d[16];
    #pragma unroll
    for (int t = 0; t < 16; ++t) d[t] = INFINITY;
    for (int j = 0; j < 64; j += 4) {
        float4 p0 = pts[base + ((j + 0 + c) & 255)];
        float4 p1 = pts[base + ((j + 1 + c) & 255)];
        float4 p2 = pts[base + ((j + 2 + c) & 255)];
        float4 p3 = pts[base + ((j + 3 + c) & 255)];
        ins16(d, dist2(me, p0)); ins16(d, dist2(me, p1));
        ins16(d, dist2(me, p2)); ins16(d, dist2(me, p3));
    }
    merge8(d);
    const float T0 = d[15];

    // ---- phase B: filter scan, per-lane predicated append (no ballots)
    const int mybase = (q * 8 + sub) * LCAP;
    int myc = 0;
    for (int j = 0; j < 256; j += 4) {
        int h0 = base + ((j + 0 + c) & 255);
        int h1 = base + ((j + 1 + c) & 255);
        int h2 = base + ((j + 2 + c) & 255);
        int h3 = base + ((j + 3 + c) & 255);
        float v0 = dist2(me, pts[h0]);
        float v1 = dist2(me, pts[h1]);
        float v2 = dist2(me, pts[h2]);
        float v3 = dist2(me, pts[h3]);
        #pragma unroll
        for (int u = 0; u < 4; ++u) {
            float v = (u == 0) ? v0 : (u == 1) ? v1 : (u == 2) ? v2 : v3;
            int   h = (u == 0) ? h0 : (u == 1) ? h1 : (u == 2) ? h2 : h3;
            if (v <= T0) {
                if (myc < LCAP) sbuf[mybase + myc] = (unsigned short)h;
                myc++;
            }
        }
    }
    if (myc > LCAP) myc = LCAP;                     // overflow P ~5e-4 (fails loudly)

    // ---- phase C: exact top16 of survivors (own list, no cross-lane) -> exact T
    #pragma unroll
    for (int t = 0; t < 16; ++t) d[t] = INFINITY;
    for (int i = 0; i < myc; ++i) {
        int h = sbuf[mybase + i];
        ins16(d, dist2(me, pts[h]));
    }
    merge8(d);
    const float T = d[15];

    // ---- phase D: emit index set (group-max loop, INF padding; ballot-append)
    int mymax = myc;
    #pragma unroll
    for (int m = 1; m < 8; m <<= 1) {
        int o = __shfl_xor(mymax, m);
        mymax = (o > mymax) ? o : mymax;
    }
    const unsigned lowm = (1u << sub) - 1;
    const int shft = lane & 56;                     // group base bit
    int nl = 0, nt = 0;
    for (int i = 0; i < mymax; ++i) {
        int h = 0; float v = INFINITY;
        if (i < myc) { h = sbuf[mybase + i]; v = dist2(me, pts[h]); }
        bool pl = (v < T), pt = (v == T);
        unsigned long long ml = __ballot(pl);
        unsigned long long mt = __ballot(pt);
        unsigned gml = (unsigned)(ml >> shft) & 0xFFu;
        unsigned gmt = (unsigned)(mt >> shft) & 0xFFu;
        if (pl) outb[q * 16 + nl + __popc(gml & lowm)] = (unsigned short)h;  // nl_total <= 15
        if (pt) { int pp = nt + __popc(gmt & lowm); if (pp < 16) tieb[q * 16 + pp] = (unsigned short)h; }
        nl += __popc(gml);
        nt += __popc(gmt);
    }
    if (sub == 0) {
        int mfill = nl;                              // < 16
        int need  = 16 - mfill;
        int tc = (nt > 16) ? 16 : nt;
        for (int s = 0; s < need; ++s) {
            int best = 0x7fffffff, bp = -1;
            for (int u = 0; u < tc; ++u) {
                int vv = tieb[q * 16 + u];
                if (vv < best) { best = vv; bp = u; }
            }
            if (bp >= 0) { tieb[q * 16 + bp] = 0xFFFF; outb[q * 16 + mfill + s] = (unsigned short)best; }
        }
    }
    __syncthreads();                                 // pts dead; outb ready

    // ---- gather + L2 pool: half-wave per query, float4 lanes (512B coalesced)
    // write pooled A directly as split-bf16 into Ahi/Alo (aliases pts)
    const float4* fb4 = (const float4*)(feat + (size_t)b * Gn * Cn);
    const int cl = lane & 31;
    #pragma unroll
    for (int pass = 0; pass < 4; ++pass) {
        int qq = w * 8 + pass * 2 + (lane >> 5);
        float4 a = make_float4(0.f, 0.f, 0.f, 0.f);
        #pragma unroll
        for (int half = 0; half < 2; ++half) {
            int hs[8]; float4 f[8];
            #pragma unroll
            for (int k = 0; k < 8; ++k) hs[k] = outb[qq * 16 + half * 8 + k];
            #pragma unroll
            for (int k = 0; k < 8; ++k) f[k] = fb4[(size_t)hs[k] * 32 + cl];
            #pragma unroll
            for (int k = 0; k < 8; ++k) {
                a.x = fmaf(f[k].x, f[k].x, a.x);
                a.y = fmaf(f[k].y, f[k].y, a.y);
                a.z = fmaf(f[k].z, f[k].z, a.z);
                a.w = fmaf(f[k].w, f[k].w, a.w);
            }
        }
        float r0 = sqrtf(a.x), r1 = sqrtf(a.y), r2 = sqrtf(a.z), r3 = sqrtf(a.w);
        unsigned short h0 = f2bf(r0), h1 = f2bf(r1), h2 = f2bf(r2), h3 = f2bf(r3);
        ushort4 hv = make_ushort4(h0, h1, h2, h3);
        ushort4 lv = make_ushort4(f2bf(r0 - bf2f(h0)), f2bf(r1 - bf2f(h1)),
                                  f2bf(r2 - bf2f(h2)), f2bf(r3 - bf2f(h3)));
        *(ushort4*)&Ahi[qq * AS + cl * 4] = hv;
        *(ushort4*)&Alo[qq * AS + cl * 4] = lv;
    }
    __syncthreads();

    // ---- MLP via split-bf16 MFMA ------------------------------------------
    // wave w: rows rowg..rowg+15 (rowg=(w&3)*16), cols colg0..colg0+63
    // A-frag: lane l -> A[rowg+(l&15)][kk + (l>>4)*8 + j]  (contiguous bf16x8)
    // B-frag: lane l -> Wt[colg0+cb*16+(l&15)][kk + (l>>4)*8 + j] (contiguous)
    // C/D:    lane l, reg r -> C[(l>>4)*4 + r][l&15]   (m89-verified)
    const int l15  = lane & 15;
    const int kofs = (lane >> 4) * 8;
    const int rowg = (w & 3) * 16;
    const int colg0 = (w >> 2) * 64;
    const unsigned short* wt1h = wt;            // +16384: lo; +32768: W2 hi; +49152: W2 lo
    f32x4 acc[4];

    // ---- layer 1: h = gelu(pooled @ W1 + b1)
    #pragma unroll
    for (int cb = 0; cb < 4; ++cb) {
        float bv = b1[colg0 + cb * 16 + l15];
        acc[cb] = (f32x4){bv, bv, bv, bv};
    }
    #pragma unroll
    for (int kk = 0; kk < 128; kk += 32) {
        bf16x8 ah = *(const bf16x8*)&Ahi[rowg * AS + l15 * AS + kk + kofs];
        bf16x8 al = *(const bf16x8*)&Alo[rowg * AS + l15 * AS + kk + kofs];
        #pragma unroll
        for (int cb = 0; cb < 4; ++cb) {
            const unsigned short* wp = wt1h + (size_t)(colg0 + cb * 16 + l15) * 128 + kk + kofs;
            bf16x8 bh = *(const bf16x8*)wp;
            bf16x8 bl = *(const bf16x8*)(wp + 16384);
            acc[cb] = __builtin_amdgcn_mfma_f32_16x16x32_bf16(ah, bh, acc[cb], 0, 0, 0);
            acc[cb] = __builtin_amdgcn_mfma_f32_16x16x32_bf16(ah, bl, acc[cb], 0, 0, 0);
            acc[cb] = __builtin_amdgcn_mfma_f32_16x16x32_bf16(al, bh, acc[cb], 0, 0, 0);
        }
    }
    __syncthreads();                            // all layer-1 A reads done
    #pragma unroll
    for (int cb = 0; cb < 4; ++cb) {
        #pragma unroll
        for (int r = 0; r < 4; ++r) {
            float gv = gelu_exact(acc[cb][r]);
            unsigned short h = f2bf(gv);
            int row = rowg + (lane >> 4) * 4 + r;
            int col = colg0 + cb * 16 + l15;
            Ahi[row * AS + col] = h;
            Alo[row * AS + col] = f2bf(gv - bf2f(h));
        }
    }
    __syncthreads();                            // h tile complete

    // ---- layer 2: out = h @ W2 + b2
    #pragma unroll
    for (int cb = 0; cb < 4; ++cb) {
        float bv = b2[colg0 + cb * 16 + l15];
        acc[cb] = (f32x4){bv, bv, bv, bv};
    }
    #pragma unroll
    for (int kk = 0; kk < 128; kk += 32) {
        bf16x8 ah = *(const bf16x8*)&Ahi[rowg * AS + l15 * AS + kk + kofs];
        bf16x8 al = *(const bf16x8*)&Alo[rowg * AS + l15 * AS + kk + kofs];
        #pragma unroll
        for (int cb = 0; cb < 4; ++cb) {
            const unsigned short* wp = wt1h + 32768 + (size_t)(colg0 + cb * 16 + l15) * 128 + kk + kofs;
            bf16x8 bh = *(const bf16x8*)wp;
            bf16x8 bl = *(const bf16x8*)(wp + 16384);
            acc[cb] = __builtin_amdgcn_mfma_f32_16x16x32_bf16(ah, bh, acc[cb], 0, 0, 0);
            acc[cb] = __builtin_amdgcn_mfma_f32_16x16x32_bf16(ah, bl, acc[cb], 0, 0, 0);
            acc[cb] = __builtin_amdgcn_mfma_f32_16x16x32_bf16(al, bh, acc[cb], 0, 0, 0);
        }
    }
    // ---- store: lanes cover 16 consecutive cols (64B segments x 4 row-groups)
    const size_t orow0 = (size_t)b * Gn + (size_t)chunk * QB + rowg + (lane >> 4) * 4;
    #pragma unroll
    for (int cb = 0; cb < 4; ++cb) {
        #pragma unroll
        for (int r = 0; r < 4; ++r) {
            out[(orow0 + r) * Cn + colg0 + cb * 16 + l15] = acc[cb][r];
        }
    }
}

// ---------------------------------------------------------------------------
extern "C" void kernel_launch(void* const* d_in, const int* in_sizes, int n_in,
                              void* d_out, int out_size, void* d_ws, size_t ws_size,
                              hipStream_t stream) {
    const float* xyz  = (const float*)d_in[0];
    const float* feat = (const float*)d_in[1];
    const float* W1   = (const float*)d_in[2];
    const float* b1   = (const float*)d_in[3];
    const float* W2   = (const float*)d_in[4];
    const float* b2   = (const float*)d_in[5];
    float* out = (float*)d_out;
    unsigned short* wt = (unsigned short*)d_ws;    // 128 KB: Wt1 hi/lo, Wt2 hi/lo

    prep_w<<<64, 256, 0, stream>>>(W1, W2, wt);
    fused_kernel<<<512, 512, 0, stream>>>(xyz, feat, b1, b2, wt, out);
}